// Round 9
// baseline (469.022 us; speedup 1.0000x reference)
//
#include <hip/hip_runtime.h>
#include <math.h>

#define BB 32
#define CC 3
#define HH 224
#define WW 224
#define HWS (HH*WW)            // 50176
#define NPIX (BB*HWS)          // 1,605,632
#define NTAPS (9*HWS)          // 451,584
#define EPS_IN 1e-5f
#define LNUM 10

// 2D tile: 8 rows x 32 cols, halo RAD=4. Taps fully precomputed:
//  twm [9][HW] float4  : bilinear weights, border-masked AND window-masked
//  tbo [9][HW] u16     : window-clamped LDS byte offset of corner cell
//  bmk [HW]    u16     : per-pixel bit mask of out-of-window taps
// Cold fixup recomputes bad taps exactly from `off` (bit-identical math).
#define TR 8
#define TC 32
#define RAD 4
#define WROWS (TR + 2*RAD)         // 16
#define WCOLS (TC + 2*RAD)         // 40
#define WCELLS (WROWS * WCOLS)     // 640
#define NTILE ((HH/TR) * (WW/TC))  // 28*7 = 196
#define NBLK (NTILE * BB)          // 6272

__device__ __forceinline__ float fast_tanh(float z) {
    z = fminf(fmaxf(z, -15.f), 15.f);
    float e = __expf(2.f * z);
    return (e - 1.f) * __frcp_rn(e + 1.f);
}

__global__ void zero_kernel(float* __restrict__ p, int n) {
    int i = blockIdx.x * 256 + threadIdx.x;
    if (i < n) p[i] = 0.f;
}

// ------- per-PIXEL tap precompute (one thread = one pixel, loops 9 taps) ----
__global__ __launch_bounds__(256) void taps_kernel(
    const float* __restrict__ off,        // [18,H,W] batch-0 offset plane
    float4* __restrict__ twm,             // [9,HW]
    unsigned short* __restrict__ tbo,     // [9,HW]
    unsigned short* __restrict__ bmk)     // [HW]
{
    int pix = blockIdx.x * 256 + threadIdx.x;    // grid exact: HWS
    int h = pix / WW, wc = pix - h * WW;
    int ty = h / TR, tx = wc / TC;
    int wly = ty * TR - RAD, wlx = tx * TC - RAD;

    unsigned bm = 0u;
    #pragma unroll
    for (int k = 0; k < 9; ++k) {
        int ky = k / 3, kx = k - 3 * ky;
        float dy = off[(2 * k)     * HWS + pix];
        float dx = off[(2 * k + 1) * HWS + pix];
        float py = (float)(h  + ky - 1) + dy;
        float px = (float)(wc + kx - 1) + dx;
        float y0f = floorf(py), x0f = floorf(px);
        float fy = py - y0f, fx = px - x0f;
        int iy0 = (int)y0f, ix0 = (int)x0f;
        int iy1 = iy0 + 1,  ix1 = ix0 + 1;
        float vy0 = (iy0 >= 0 && iy0 < HH) ? 1.f : 0.f;
        float vy1 = (iy1 >= 0 && iy1 < HH) ? 1.f : 0.f;
        float vx0 = (ix0 >= 0 && ix0 < WW) ? 1.f : 0.f;
        float vx1 = (ix1 >= 0 && ix1 < WW) ? 1.f : 0.f;

        int cy = iy0 - wly, cx = ix0 - wlx;
        bool inw = ((unsigned)cy <= (unsigned)(WROWS - 2)) &&
                   ((unsigned)cx <= (unsigned)(WCOLS - 2));
        float m = inw ? 1.f : 0.f;
        if (!inw) bm |= 1u << k;

        float4 w;
        w.x = (1.f - fy) * (1.f - fx) * vy0 * vx0 * m;
        w.y = (1.f - fy) * fx         * vy0 * vx1 * m;
        w.z = fy         * (1.f - fx) * vy1 * vx0 * m;
        w.w = fy         * fx         * vy1 * vx1 * m;
        twm[k * HWS + pix] = w;

        int cell = min(max(cy, 0), WROWS - 2) * WCOLS + min(max(cx, 0), WCOLS - 2);
        tbo[k * HWS + pix] = (unsigned short)(cell * 16);
    }
    bmk[pix] = (unsigned short)bm;
}

__global__ __launch_bounds__(256) void pack_kernel(
    const float* __restrict__ x, float4* __restrict__ xi)
{
    int g = blockIdx.x * 256 + threadIdx.x;
    int b = g / HWS, pix = g - b * HWS;
    const float* xb = x + (size_t)b * (CC * HWS) + pix;
    xi[g] = make_float4(xb[0], xb[HWS], xb[2 * HWS], 0.f);
}

// R9: occupancy boost. R8 model: LDS pipe (~560-660 cyc/wave) is now the
// heaviest resource (~20-27us floor) but conv ran ~42us -> only ~50-65%
// LDS utilization at 4 blocks/CU ((256,4), occupancy 47%). Slim VGPRs:
// twm streamed in-loop (was a 36-VGPR hoist; under the tighter cap the
// compiler prefetches as far as registers allow), tbk hoist kept (9 regs).
// launch_bounds(256,6): VGPR cap ~85, target 6 blocks/CU = 24 waves/CU so
// other waves' hot loops cover each block's staging/barrier phase.
// Tap L2 locality: XCD swizzle keeps a tile-chunk's 32 batches on one XCD
// (~1 MB tap working set per XCD -> L2-resident despite streaming).
template<int DO_NORM>
__global__ __launch_bounds__(256, 6) void conv_fused(
    const float4* __restrict__ xi,        // prev RAW activations [B*HWS]
    const float4* __restrict__ twm,       // [9,HW]
    const unsigned short* __restrict__ tbo,
    const unsigned short* __restrict__ bmk,
    const float* __restrict__ off,        // exact cold fixup
    const float* __restrict__ wt,         // [3,3,9] -> SGPRs via s_load
    const float* __restrict__ stats_in,   // [B*3][2] prev layer
    const float* __restrict__ gamma,
    const float* __restrict__ beta,
    float4* __restrict__ yo,              // RAW conv out [B*HWS]
    float* __restrict__ stats_out)        // [B*3][2] this layer
{
    __shared__ float4 win[WCELLS];
    __shared__ float  red[4][8][6];

    int t = threadIdx.x;

    int p = blockIdx.x;
    int logical = (p & 7) * (NBLK / 8) + (p >> 3);
    int b    = logical & 31;
    int tile = logical >> 5;             // 0..195
    int ty = tile / 7, tx = tile - ty * 7;
    int by0 = ty * TR, bx0 = tx * TC;
    int wly = by0 - RAD, wlx = bx0 - RAD;

    const float4* xb = xi + (size_t)b * HWS;

    int ry = t >> 5, rx = t & 31;
    int pix = (by0 + ry) * WW + (bx0 + rx);

    // hoist only the cheap tap data: LDS byte offsets (9 regs) + bad mask
    int tbk[9];
    #pragma unroll
    for (int k = 0; k < 9; ++k) tbk[k] = tbo[k * HWS + pix];
    unsigned bad = bmk[pix];

    // uniform per-(b,c) norm params of the PREVIOUS layer
    float mean0=0.f, mean1=0.f, mean2=0.f;
    float g0=1.f, g1=1.f, g2=1.f, bt0=0.f, bt1=0.f, bt2=0.f;
    if (DO_NORM) {
        const float* st = stats_in + b * 6;
        mean0 = st[0] * (1.f/HWS); mean1 = st[2] * (1.f/HWS); mean2 = st[4] * (1.f/HWS);
        float v0 = fmaxf(st[1]*(1.f/HWS) - mean0*mean0, 0.f);
        float v1 = fmaxf(st[3]*(1.f/HWS) - mean1*mean1, 0.f);
        float v2 = fmaxf(st[5]*(1.f/HWS) - mean2*mean2, 0.f);
        g0 = gamma[0] * rsqrtf(v0 + EPS_IN); bt0 = beta[0];
        g1 = gamma[1] * rsqrtf(v1 + EPS_IN); bt1 = beta[1];
        g2 = gamma[2] * rsqrtf(v2 + EPS_IN); bt2 = beta[2];
    }

    // ---- stage window (norm+tanh of prev layer applied on the fly) ----
    #pragma unroll
    for (int i = 0; i < 3; ++i) {
        int cell = t + i * 256;
        if (cell < WCELLS) {
            int wy = cell / WCOLS, wx = cell - wy * WCOLS;
            int gy = min(max(wly + wy, 0), HH - 1);   // clamp: value only used
            int gx = min(max(wlx + wx, 0), WW - 1);   // when weight != 0
            float4 v = xb[gy * WW + gx];
            if (DO_NORM) {
                v.x = fast_tanh((v.x - mean0) * g0 + bt0);
                v.y = fast_tanh((v.y - mean1) * g1 + bt1);
                v.z = fast_tanh((v.z - mean2) * g2 + bt2);
            }
            win[cell] = v;
        }
    }
    __syncthreads();

    float acc0 = 0.f, acc1 = 0.f, acc2 = 0.f;

    #pragma unroll
    for (int k = 0; k < 9; ++k) {
        float4 w = twm[k * HWS + pix];    // streamed; compiler prefetches
        const float4* c = (const float4*)((const char*)win + tbk[k]);
        float4 v = c[0];
        float s0 = v.x * w.x, s1 = v.y * w.x, s2 = v.z * w.x;
        v = c[1];
        s0 = fmaf(v.x, w.y, s0); s1 = fmaf(v.y, w.y, s1); s2 = fmaf(v.z, w.y, s2);
        v = c[WCOLS];
        s0 = fmaf(v.x, w.z, s0); s1 = fmaf(v.y, w.z, s1); s2 = fmaf(v.z, w.z, s2);
        v = c[WCOLS + 1];
        s0 = fmaf(v.x, w.w, s0); s1 = fmaf(v.y, w.w, s1); s2 = fmaf(v.z, w.w, s2);

        // wt[] with constant indices: uniform address -> s_load -> SGPR operand
        acc0 = fmaf(s2, wt[18 + k], fmaf(s1, wt[ 9 + k], fmaf(s0, wt[     k], acc0)));
        acc1 = fmaf(s2, wt[45 + k], fmaf(s1, wt[36 + k], fmaf(s0, wt[27 + k], acc1)));
        acc2 = fmaf(s2, wt[72 + k], fmaf(s1, wt[63 + k], fmaf(s0, wt[54 + k], acc2)));
    }

    // ---- COLD fixup: out-of-window taps; recompute exactly from `off` ----
    if (__builtin_expect(bad != 0u, 0)) {
        int h = pix / WW, wc = pix - h * WW;
        unsigned bb = bad;
        while (bb) {
            int k = __ffs(bb) - 1; bb &= bb - 1;
            int ky = k / 3, kx = k - 3 * ky;
            float dy = off[(2 * k)     * HWS + pix];
            float dx = off[(2 * k + 1) * HWS + pix];
            float py = (float)(h  + ky - 1) + dy;
            float px = (float)(wc + kx - 1) + dx;
            float y0f = floorf(py), x0f = floorf(px);
            float fy = py - y0f, fx = px - x0f;
            int iy0 = (int)y0f, ix0 = (int)x0f;
            int iy1 = iy0 + 1,  ix1 = ix0 + 1;
            float vy0 = (iy0 >= 0 && iy0 < HH) ? 1.f : 0.f;
            float vy1 = (iy1 >= 0 && iy1 < HH) ? 1.f : 0.f;
            float vx0 = (ix0 >= 0 && ix0 < WW) ? 1.f : 0.f;
            float vx1 = (ix1 >= 0 && ix1 < WW) ? 1.f : 0.f;
            float w00 = (1.f - fy) * (1.f - fx) * vy0 * vx0;
            float w01 = (1.f - fy) * fx         * vy0 * vx1;
            float w10 = fy         * (1.f - fx) * vy1 * vx0;
            float w11 = fy         * fx         * vy1 * vx1;
            int cy0 = min(max(iy0, 0), HH - 1), cy1 = min(max(iy1, 0), HH - 1);
            int cx0 = min(max(ix0, 0), WW - 1), cx1 = min(max(ix1, 0), WW - 1);
            float s0, s1, s2;
            float4 v = xb[cy0 * WW + cx0];
            if (DO_NORM) { v.x = fast_tanh((v.x-mean0)*g0+bt0); v.y = fast_tanh((v.y-mean1)*g1+bt1); v.z = fast_tanh((v.z-mean2)*g2+bt2); }
            s0 = v.x * w00; s1 = v.y * w00; s2 = v.z * w00;
            v = xb[cy0 * WW + cx1];
            if (DO_NORM) { v.x = fast_tanh((v.x-mean0)*g0+bt0); v.y = fast_tanh((v.y-mean1)*g1+bt1); v.z = fast_tanh((v.z-mean2)*g2+bt2); }
            s0 = fmaf(v.x, w01, s0); s1 = fmaf(v.y, w01, s1); s2 = fmaf(v.z, w01, s2);
            v = xb[cy1 * WW + cx0];
            if (DO_NORM) { v.x = fast_tanh((v.x-mean0)*g0+bt0); v.y = fast_tanh((v.y-mean1)*g1+bt1); v.z = fast_tanh((v.z-mean2)*g2+bt2); }
            s0 = fmaf(v.x, w10, s0); s1 = fmaf(v.y, w10, s1); s2 = fmaf(v.z, w10, s2);
            v = xb[cy1 * WW + cx1];
            if (DO_NORM) { v.x = fast_tanh((v.x-mean0)*g0+bt0); v.y = fast_tanh((v.y-mean1)*g1+bt1); v.z = fast_tanh((v.z-mean2)*g2+bt2); }
            s0 = fmaf(v.x, w11, s0); s1 = fmaf(v.y, w11, s1); s2 = fmaf(v.z, w11, s2);
            acc0 = fmaf(s2, wt[18 + k], fmaf(s1, wt[ 9 + k], fmaf(s0, wt[     k], acc0)));
            acc1 = fmaf(s2, wt[45 + k], fmaf(s1, wt[36 + k], fmaf(s0, wt[27 + k], acc1)));
            acc2 = fmaf(s2, wt[72 + k], fmaf(s1, wt[63 + k], fmaf(s0, wt[54 + k], acc2)));
        }
    }

    yo[(size_t)b * HWS + pix] = make_float4(acc0, acc1, acc2, 0.f);

    // ---- per-(b,channel) sum/sumsq: 3-level butterfly (stop at 8 lanes) ----
    float s0r = acc0, q0 = acc0 * acc0;
    float s1r = acc1, q1 = acc1 * acc1;
    float s2r = acc2, q2 = acc2 * acc2;
    #pragma unroll
    for (int o = 32; o >= 8; o >>= 1) {
        s0r += __shfl_down(s0r, o); q0 += __shfl_down(q0, o);
        s1r += __shfl_down(s1r, o); q1 += __shfl_down(q1, o);
        s2r += __shfl_down(s2r, o); q2 += __shfl_down(q2, o);
    }
    int wave = t >> 6, lane = t & 63;
    if (lane < 8) {
        red[wave][lane][0] = s0r; red[wave][lane][1] = q0;
        red[wave][lane][2] = s1r; red[wave][lane][3] = q1;
        red[wave][lane][4] = s2r; red[wave][lane][5] = q2;
    }
    __syncthreads();
    if (t < 6) {
        float v = 0.f;
        #pragma unroll
        for (int w = 0; w < 4; ++w)
            #pragma unroll
            for (int s = 0; s < 8; ++s)
                v += red[w][s][t];
        int ch = t >> 1, which = t & 1;
        atomicAdd(&stats_out[(b * 3 + ch) * 2 + which], v);
    }
}

__global__ __launch_bounds__(256) void norm_final(
    const float4* __restrict__ y, float* __restrict__ outp,
    const float* __restrict__ stats,
    const float* __restrict__ gamma, const float* __restrict__ beta)
{
    int q = blockIdx.x;
    int logical = (q & 7) * ((NPIX/256) / 8) + (q >> 3);
    int b     = logical & 31;
    int chunk = logical >> 5;
    int pix   = chunk * 256 + threadIdx.x;

    float4 v = y[b * HWS + pix];
    float vin[3] = {v.x, v.y, v.z};
    float r[3];
    #pragma unroll
    for (int c = 0; c < 3; ++c) {
        float s  = stats[(b * 3 + c) * 2 + 0];
        float qq = stats[(b * 3 + c) * 2 + 1];
        float mean = s * (1.f / HWS);
        float var  = fmaxf(qq * (1.f / HWS) - mean * mean, 0.f);
        float gsc  = gamma[c] * rsqrtf(var + EPS_IN);
        r[c] = fast_tanh((vin[c] - mean) * gsc + beta[c]);
    }
    float* ob = outp + (size_t)b * (CC * HWS) + pix;
    ob[0]       = r[0];
    ob[HWS]     = r[1];
    ob[2 * HWS] = r[2];
}

extern "C" void kernel_launch(void* const* d_in, const int* in_sizes, int n_in,
                              void* d_out, int out_size, void* d_ws, size_t ws_size,
                              hipStream_t stream) {
    const float* x     = (const float*)d_in[0];
    const float* wt    = (const float*)d_in[1];
    const float* off   = (const float*)d_in[2];
    const float* gamma = (const float*)d_in[3];
    const float* beta  = (const float*)d_in[4];

    float* out  = (float*)d_out;
    float*          bufA = (float*)d_ws;                              // 25.7 MB
    float*          bufB = bufA + (size_t)NPIX * 4;                   // 25.7 MB
    float4*         twm  = (float4*)(bufB + (size_t)NPIX * 4);        // 7.2 MB
    unsigned short* tbo  = (unsigned short*)((char*)twm + (size_t)NTAPS * 16); // 0.9 MB
    unsigned short* bmk  = (unsigned short*)((char*)tbo + (size_t)NTAPS * 2);  // 0.1 MB
    float*          stats = (float*)((char*)bmk + (size_t)HWS * 2);   // 7.7 KB
    // ws total ~= 60 MB

    zero_kernel<<<(LNUM * 192 + 255) / 256, 256, 0, stream>>>(stats, LNUM * 192);
    taps_kernel<<<HWS / 256, 256, 0, stream>>>(off, twm, tbo, bmk);
    pack_kernel<<<NPIX / 256, 256, 0, stream>>>(x, (float4*)bufB);

    const float4* cur = (const float4*)bufB;
    const float* st_prev = nullptr;
    for (int it = 0; it < LNUM; ++it) {
        float4* dst = (float4*)((it & 1) ? bufB : bufA);
        float* st = stats + it * 192;
        if (it == 0)
            conv_fused<0><<<NBLK, 256, 0, stream>>>(cur, twm, tbo, bmk, off, wt, nullptr,
                                                    gamma, beta, dst, st);
        else
            conv_fused<1><<<NBLK, 256, 0, stream>>>(cur, twm, tbo, bmk, off, wt, st_prev,
                                                    gamma, beta, dst, st);
        cur = dst;
        st_prev = st;
    }
    norm_final<<<NPIX / 256, 256, 0, stream>>>(cur, out, st_prev, gamma, beta);
}

// Round 11
// 462.989 us; speedup vs baseline: 1.0130x; 1.0130x over previous
//
#include <hip/hip_runtime.h>
#include <math.h>

#define BB 32
#define CC 3
#define HH 224
#define WW 224
#define HWS (HH*WW)            // 50176
#define NPIX (BB*HWS)          // 1,605,632
#define NTAPS (9*HWS)          // 451,584
#define EPS_IN 1e-5f
#define LNUM 10

// 2D tile: 8 rows x 32 cols, halo RAD=4. Taps fully precomputed:
//  twm [9][HW] float4 : bilinear weights, border- AND window-masked
//  tmo4 [HW] int4     : LDS byte offsets of taps k=0..7 (u16 pairs)
//  tmx  [HW] u32      : offset k=8 | bad-mask<<16
// Cold fixup recomputes bad taps exactly from `off` (bit-identical math).
#define TR 8
#define TC 32
#define RAD 4
#define WROWS (TR + 2*RAD)         // 16
#define WCOLS (TC + 2*RAD)         // 40
#define WCELLS (WROWS * WCOLS)     // 640
#define NTILE ((HH/TR) * (WW/TC))  // 28*7 = 196
#define NBLK (NTILE * BB)          // 6272

typedef float f3v __attribute__((ext_vector_type(3)));   // 12B LDS reads (b96)

// tanh(z) = 1 - 2/(exp(2z)+1); saturates exactly (exp->inf => 1, ->0 => -1),
// no clamp needed. 5 VALU.
__device__ __forceinline__ float fast_tanh(float z) {
    float e = __expf(2.f * z);
    return fmaf(-2.f, __frcp_rn(e + 1.f), 1.f);
}

__global__ void zero_kernel(float* __restrict__ p, int n) {
    int i = blockIdx.x * 256 + threadIdx.x;
    if (i < n) p[i] = 0.f;
}

// ------- per-PIXEL tap precompute (one thread = one pixel, loops 9 taps) ----
__global__ __launch_bounds__(256) void taps_kernel(
    const float* __restrict__ off,        // [18,H,W] batch-0 offset plane
    float4* __restrict__ twm,             // [9,HW]
    int4* __restrict__ tmo4,              // [HW]
    unsigned int* __restrict__ tmx)       // [HW]
{
    int pix = blockIdx.x * 256 + threadIdx.x;    // grid exact: HWS
    int h = pix / WW, wc = pix - h * WW;
    int ty = h / TR, tx = wc / TC;
    int wly = ty * TR - RAD, wlx = tx * TC - RAD;

    unsigned bm = 0u;
    unsigned offs[9];
    #pragma unroll
    for (int k = 0; k < 9; ++k) {
        int ky = k / 3, kx = k - 3 * ky;
        float dy = off[(2 * k)     * HWS + pix];
        float dx = off[(2 * k + 1) * HWS + pix];
        float py = (float)(h  + ky - 1) + dy;
        float px = (float)(wc + kx - 1) + dx;
        float y0f = floorf(py), x0f = floorf(px);
        float fy = py - y0f, fx = px - x0f;
        int iy0 = (int)y0f, ix0 = (int)x0f;
        int iy1 = iy0 + 1,  ix1 = ix0 + 1;
        float vy0 = (iy0 >= 0 && iy0 < HH) ? 1.f : 0.f;
        float vy1 = (iy1 >= 0 && iy1 < HH) ? 1.f : 0.f;
        float vx0 = (ix0 >= 0 && ix0 < WW) ? 1.f : 0.f;
        float vx1 = (ix1 >= 0 && ix1 < WW) ? 1.f : 0.f;

        int cy = iy0 - wly, cx = ix0 - wlx;
        bool inw = ((unsigned)cy <= (unsigned)(WROWS - 2)) &&
                   ((unsigned)cx <= (unsigned)(WCOLS - 2));
        float m = inw ? 1.f : 0.f;
        if (!inw) bm |= 1u << k;

        float4 w;
        w.x = (1.f - fy) * (1.f - fx) * vy0 * vx0 * m;
        w.y = (1.f - fy) * fx         * vy0 * vx1 * m;
        w.z = fy         * (1.f - fx) * vy1 * vx0 * m;
        w.w = fy         * fx         * vy1 * vx1 * m;
        twm[k * HWS + pix] = w;

        int cell = min(max(cy, 0), WROWS - 2) * WCOLS + min(max(cx, 0), WCOLS - 2);
        offs[k] = (unsigned)(cell * 16);
    }
    int4 m4;
    m4.x = (int)(offs[0] | (offs[1] << 16));
    m4.y = (int)(offs[2] | (offs[3] << 16));
    m4.z = (int)(offs[4] | (offs[5] << 16));
    m4.w = (int)(offs[6] | (offs[7] << 16));
    tmo4[pix] = m4;
    tmx[pix]  = offs[8] | (bm << 16);
}

__global__ __launch_bounds__(256) void pack_kernel(
    const float* __restrict__ x, float4* __restrict__ xi)
{
    int g = blockIdx.x * 256 + threadIdx.x;
    int b = g / HWS, pix = g - b * HWS;
    const float* xb = x + (size_t)b * (CC * HWS) + pix;
    xi[g] = make_float4(xb[0], xb[HWS], xb[2 * HWS], 0.f);
}

// R11 (= R10 with the __exp2f -> __expf compile fix): DS-pipe trim.
//  (1) corner reads as <3 x float> on the 16B-stride window -> ds_read_b96:
//      12B moved instead of 16B per corner (the .w lane was never used)
//  (2) tap metadata packed pixel-major: int4+u32 (2 coalesced loads vs 10)
//  (3) exp-form tanh: 5 VALU, exact saturation, no clamp
//  Config: R8's best, (256,4) + hoisted twk[9].
template<int DO_NORM>
__global__ __launch_bounds__(256, 4) void conv_fused(
    const float4* __restrict__ xi,        // prev RAW activations [B*HWS]
    const float4* __restrict__ twm,       // [9,HW]
    const int4* __restrict__ tmo4,        // [HW]
    const unsigned int* __restrict__ tmx, // [HW]
    const float* __restrict__ off,        // exact cold fixup
    const float* __restrict__ wt,         // [3,3,9] -> SGPRs via s_load
    const float* __restrict__ stats_in,   // [B*3][2] prev layer
    const float* __restrict__ gamma,
    const float* __restrict__ beta,
    float4* __restrict__ yo,              // RAW conv out [B*HWS]
    float* __restrict__ stats_out)        // [B*3][2] this layer
{
    __shared__ float4 win[WCELLS];
    __shared__ float  red[4][8][6];

    int t = threadIdx.x;

    int p = blockIdx.x;
    int logical = (p & 7) * (NBLK / 8) + (p >> 3);
    int b    = logical & 31;
    int tile = logical >> 5;             // 0..195
    int ty = tile / 7, tx = tile - ty * 7;
    int by0 = ty * TR, bx0 = tx * TC;
    int wly = by0 - RAD, wlx = bx0 - RAD;

    const float4* xb = xi + (size_t)b * HWS;

    int ry = t >> 5, rx = t & 31;
    int pix = (by0 + ry) * WW + (bx0 + rx);

    // packed tap metadata: 2 loads -> 9 offsets + bad mask
    int4 m4 = tmo4[pix];
    unsigned mx = tmx[pix];
    int tbk[9];
    tbk[0] = ((unsigned)m4.x) & 0xffff; tbk[1] = ((unsigned)m4.x) >> 16;
    tbk[2] = ((unsigned)m4.y) & 0xffff; tbk[3] = ((unsigned)m4.y) >> 16;
    tbk[4] = ((unsigned)m4.z) & 0xffff; tbk[5] = ((unsigned)m4.z) >> 16;
    tbk[6] = ((unsigned)m4.w) & 0xffff; tbk[7] = ((unsigned)m4.w) >> 16;
    tbk[8] = mx & 0xffff;
    unsigned bad = mx >> 16;

    // hoist tap weights (36 VGPR) — R8 best config
    float4 twk[9];
    #pragma unroll
    for (int k = 0; k < 9; ++k) twk[k] = twm[k * HWS + pix];

    // uniform per-(b,c) norm params of the PREVIOUS layer
    float mean0=0.f, mean1=0.f, mean2=0.f;
    float g0=1.f, g1=1.f, g2=1.f, bt0=0.f, bt1=0.f, bt2=0.f;
    if (DO_NORM) {
        const float* st = stats_in + b * 6;
        mean0 = st[0] * (1.f/HWS); mean1 = st[2] * (1.f/HWS); mean2 = st[4] * (1.f/HWS);
        float v0 = fmaxf(st[1]*(1.f/HWS) - mean0*mean0, 0.f);
        float v1 = fmaxf(st[3]*(1.f/HWS) - mean1*mean1, 0.f);
        float v2 = fmaxf(st[5]*(1.f/HWS) - mean2*mean2, 0.f);
        g0 = gamma[0] * rsqrtf(v0 + EPS_IN); bt0 = beta[0];
        g1 = gamma[1] * rsqrtf(v1 + EPS_IN); bt1 = beta[1];
        g2 = gamma[2] * rsqrtf(v2 + EPS_IN); bt2 = beta[2];
    }

    // ---- stage window (norm+tanh of prev layer applied on the fly) ----
    #pragma unroll
    for (int i = 0; i < 3; ++i) {
        int cell = t + i * 256;
        if (cell < WCELLS) {
            int wy = cell / WCOLS, wx = cell - wy * WCOLS;
            int gy = min(max(wly + wy, 0), HH - 1);   // clamp: value only used
            int gx = min(max(wlx + wx, 0), WW - 1);   // when weight != 0
            float4 v = xb[gy * WW + gx];
            if (DO_NORM) {
                v.x = fast_tanh((v.x - mean0) * g0 + bt0);
                v.y = fast_tanh((v.y - mean1) * g1 + bt1);
                v.z = fast_tanh((v.z - mean2) * g2 + bt2);
            }
            win[cell] = v;
        }
    }
    __syncthreads();

    float acc0 = 0.f, acc1 = 0.f, acc2 = 0.f;

    #pragma unroll
    for (int k = 0; k < 9; ++k) {
        float4 w = twk[k];
        const char* cp = (const char*)win + tbk[k];
        f3v v = *(const f3v*)cp;                            // ds_read_b96
        float s0 = v.x * w.x, s1 = v.y * w.x, s2 = v.z * w.x;
        v = *(const f3v*)(cp + 16);
        s0 = fmaf(v.x, w.y, s0); s1 = fmaf(v.y, w.y, s1); s2 = fmaf(v.z, w.y, s2);
        v = *(const f3v*)(cp + 16 * WCOLS);
        s0 = fmaf(v.x, w.z, s0); s1 = fmaf(v.y, w.z, s1); s2 = fmaf(v.z, w.z, s2);
        v = *(const f3v*)(cp + 16 * WCOLS + 16);
        s0 = fmaf(v.x, w.w, s0); s1 = fmaf(v.y, w.w, s1); s2 = fmaf(v.z, w.w, s2);

        // wt[] with constant indices: uniform address -> s_load -> SGPR operand
        acc0 = fmaf(s2, wt[18 + k], fmaf(s1, wt[ 9 + k], fmaf(s0, wt[     k], acc0)));
        acc1 = fmaf(s2, wt[45 + k], fmaf(s1, wt[36 + k], fmaf(s0, wt[27 + k], acc1)));
        acc2 = fmaf(s2, wt[72 + k], fmaf(s1, wt[63 + k], fmaf(s0, wt[54 + k], acc2)));
    }

    // ---- COLD fixup: out-of-window taps; recompute exactly from `off` ----
    if (__builtin_expect(bad != 0u, 0)) {
        int h = pix / WW, wc = pix - h * WW;
        unsigned bb = bad;
        while (bb) {
            int k = __ffs(bb) - 1; bb &= bb - 1;
            int ky = k / 3, kx = k - 3 * ky;
            float dy = off[(2 * k)     * HWS + pix];
            float dx = off[(2 * k + 1) * HWS + pix];
            float py = (float)(h  + ky - 1) + dy;
            float px = (float)(wc + kx - 1) + dx;
            float y0f = floorf(py), x0f = floorf(px);
            float fy = py - y0f, fx = px - x0f;
            int iy0 = (int)y0f, ix0 = (int)x0f;
            int iy1 = iy0 + 1,  ix1 = ix0 + 1;
            float vy0 = (iy0 >= 0 && iy0 < HH) ? 1.f : 0.f;
            float vy1 = (iy1 >= 0 && iy1 < HH) ? 1.f : 0.f;
            float vx0 = (ix0 >= 0 && ix0 < WW) ? 1.f : 0.f;
            float vx1 = (ix1 >= 0 && ix1 < WW) ? 1.f : 0.f;
            float w00 = (1.f - fy) * (1.f - fx) * vy0 * vx0;
            float w01 = (1.f - fy) * fx         * vy0 * vx1;
            float w10 = fy         * (1.f - fx) * vy1 * vx0;
            float w11 = fy         * fx         * vy1 * vx1;
            int cy0 = min(max(iy0, 0), HH - 1), cy1 = min(max(iy1, 0), HH - 1);
            int cx0 = min(max(ix0, 0), WW - 1), cx1 = min(max(ix1, 0), WW - 1);
            float s0, s1, s2;
            float4 v = xb[cy0 * WW + cx0];
            if (DO_NORM) { v.x = fast_tanh((v.x-mean0)*g0+bt0); v.y = fast_tanh((v.y-mean1)*g1+bt1); v.z = fast_tanh((v.z-mean2)*g2+bt2); }
            s0 = v.x * w00; s1 = v.y * w00; s2 = v.z * w00;
            v = xb[cy0 * WW + cx1];
            if (DO_NORM) { v.x = fast_tanh((v.x-mean0)*g0+bt0); v.y = fast_tanh((v.y-mean1)*g1+bt1); v.z = fast_tanh((v.z-mean2)*g2+bt2); }
            s0 = fmaf(v.x, w01, s0); s1 = fmaf(v.y, w01, s1); s2 = fmaf(v.z, w01, s2);
            v = xb[cy1 * WW + cx0];
            if (DO_NORM) { v.x = fast_tanh((v.x-mean0)*g0+bt0); v.y = fast_tanh((v.y-mean1)*g1+bt1); v.z = fast_tanh((v.z-mean2)*g2+bt2); }
            s0 = fmaf(v.x, w10, s0); s1 = fmaf(v.y, w10, s1); s2 = fmaf(v.z, w10, s2);
            v = xb[cy1 * WW + cx1];
            if (DO_NORM) { v.x = fast_tanh((v.x-mean0)*g0+bt0); v.y = fast_tanh((v.y-mean1)*g1+bt1); v.z = fast_tanh((v.z-mean2)*g2+bt2); }
            s0 = fmaf(v.x, w11, s0); s1 = fmaf(v.y, w11, s1); s2 = fmaf(v.z, w11, s2);
            acc0 = fmaf(s2, wt[18 + k], fmaf(s1, wt[ 9 + k], fmaf(s0, wt[     k], acc0)));
            acc1 = fmaf(s2, wt[45 + k], fmaf(s1, wt[36 + k], fmaf(s0, wt[27 + k], acc1)));
            acc2 = fmaf(s2, wt[72 + k], fmaf(s1, wt[63 + k], fmaf(s0, wt[54 + k], acc2)));
        }
    }

    yo[(size_t)b * HWS + pix] = make_float4(acc0, acc1, acc2, 0.f);

    // ---- per-(b,channel) sum/sumsq: 3-level butterfly (stop at 8 lanes) ----
    float s0r = acc0, q0 = acc0 * acc0;
    float s1r = acc1, q1 = acc1 * acc1;
    float s2r = acc2, q2 = acc2 * acc2;
    #pragma unroll
    for (int o = 32; o >= 8; o >>= 1) {
        s0r += __shfl_down(s0r, o); q0 += __shfl_down(q0, o);
        s1r += __shfl_down(s1r, o); q1 += __shfl_down(q1, o);
        s2r += __shfl_down(s2r, o); q2 += __shfl_down(q2, o);
    }
    int wave = t >> 6, lane = t & 63;
    if (lane < 8) {
        red[wave][lane][0] = s0r; red[wave][lane][1] = q0;
        red[wave][lane][2] = s1r; red[wave][lane][3] = q1;
        red[wave][lane][4] = s2r; red[wave][lane][5] = q2;
    }
    __syncthreads();
    if (t < 6) {
        float v = 0.f;
        #pragma unroll
        for (int w = 0; w < 4; ++w)
            #pragma unroll
            for (int s = 0; s < 8; ++s)
                v += red[w][s][t];
        int ch = t >> 1, which = t & 1;
        atomicAdd(&stats_out[(b * 3 + ch) * 2 + which], v);
    }
}

__global__ __launch_bounds__(256) void norm_final(
    const float4* __restrict__ y, float* __restrict__ outp,
    const float* __restrict__ stats,
    const float* __restrict__ gamma, const float* __restrict__ beta)
{
    int q = blockIdx.x;
    int logical = (q & 7) * ((NPIX/256) / 8) + (q >> 3);
    int b     = logical & 31;
    int chunk = logical >> 5;
    int pix   = chunk * 256 + threadIdx.x;

    float4 v = y[b * HWS + pix];
    float vin[3] = {v.x, v.y, v.z};
    float r[3];
    #pragma unroll
    for (int c = 0; c < 3; ++c) {
        float s  = stats[(b * 3 + c) * 2 + 0];
        float qq = stats[(b * 3 + c) * 2 + 1];
        float mean = s * (1.f / HWS);
        float var  = fmaxf(qq * (1.f / HWS) - mean * mean, 0.f);
        float gsc  = gamma[c] * rsqrtf(var + EPS_IN);
        r[c] = fast_tanh((vin[c] - mean) * gsc + beta[c]);
    }
    float* ob = outp + (size_t)b * (CC * HWS) + pix;
    ob[0]       = r[0];
    ob[HWS]     = r[1];
    ob[2 * HWS] = r[2];
}

extern "C" void kernel_launch(void* const* d_in, const int* in_sizes, int n_in,
                              void* d_out, int out_size, void* d_ws, size_t ws_size,
                              hipStream_t stream) {
    const float* x     = (const float*)d_in[0];
    const float* wt    = (const float*)d_in[1];
    const float* off   = (const float*)d_in[2];
    const float* gamma = (const float*)d_in[3];
    const float* beta  = (const float*)d_in[4];

    float* out  = (float*)d_out;
    float*        bufA = (float*)d_ws;                              // 25.7 MB
    float*        bufB = bufA + (size_t)NPIX * 4;                   // 25.7 MB
    float4*       twm  = (float4*)(bufB + (size_t)NPIX * 4);        // 7.2 MB
    int4*         tmo4 = (int4*)((char*)twm + (size_t)NTAPS * 16);  // 0.8 MB
    unsigned int* tmx  = (unsigned int*)((char*)tmo4 + (size_t)HWS * 16); // 0.2 MB
    float*        stats = (float*)((char*)tmx + (size_t)HWS * 4);   // 7.7 KB
    // ws total ~= 60 MB

    zero_kernel<<<(LNUM * 192 + 255) / 256, 256, 0, stream>>>(stats, LNUM * 192);
    taps_kernel<<<HWS / 256, 256, 0, stream>>>(off, twm, tmo4, tmx);
    pack_kernel<<<NPIX / 256, 256, 0, stream>>>(x, (float4*)bufB);

    const float4* cur = (const float4*)bufB;
    const float* st_prev = nullptr;
    for (int it = 0; it < LNUM; ++it) {
        float4* dst = (float4*)((it & 1) ? bufB : bufA);
        float* st = stats + it * 192;
        if (it == 0)
            conv_fused<0><<<NBLK, 256, 0, stream>>>(cur, twm, tmo4, tmx, off, wt, nullptr,
                                                    gamma, beta, dst, st);
        else
            conv_fused<1><<<NBLK, 256, 0, stream>>>(cur, twm, tmo4, tmx, off, wt, st_prev,
                                                    gamma, beta, dst, st);
        cur = dst;
        st_prev = st;
    }
    norm_final<<<NPIX / 256, 256, 0, stream>>>(cur, out, st_prev, gamma, beta);
}